// Round 1
// baseline (325.152 us; speedup 1.0000x reference)
//
#include <hip/hip_runtime.h>

#define N_NODES 50000
#define N_EDGES 800000
#define N_FEAT 128
#define N_HIDDEN 64
#define LRELU_ALPHA 0.05f

// ---------------------------------------------------------------------------
// K1: z = x @ W_fc  [N,64]; s_dst = z @ a_w[:64]; s_src = z @ a_w[64:]
// One wave (64 lanes) per node; lane = hidden unit. W_fc staged in LDS (32KB).
// ---------------------------------------------------------------------------
__global__ __launch_bounds__(256) void k1_fc_scores(
    const float* __restrict__ x, const float* __restrict__ W,
    const float* __restrict__ a_w,
    float* __restrict__ z, float* __restrict__ s_dst, float* __restrict__ s_src)
{
    __shared__ float Wl[N_FEAT * N_HIDDEN];   // 32 KB
    __shared__ float xl[4][N_FEAT];           // 2 KB

    const int tid  = threadIdx.x;
    const int wave = tid >> 6;
    const int lane = tid & 63;
    const int node = blockIdx.x * 4 + wave;

    // cooperative load of W_fc into LDS (coalesced)
    for (int i = tid; i < N_FEAT * N_HIDDEN; i += 256) Wl[i] = W[i];

    if (node < N_NODES) {
        xl[wave][lane]      = x[node * N_FEAT + lane];
        xl[wave][lane + 64] = x[node * N_FEAT + 64 + lane];
    }
    __syncthreads();
    if (node >= N_NODES) return;

    float acc = 0.f;
    #pragma unroll
    for (int k = 0; k < N_FEAT; ++k)
        acc = fmaf(xl[wave][k], Wl[k * N_HIDDEN + lane], acc);

    z[node * N_HIDDEN + lane] = acc;

    // per-node score partials: dot(z_row, a1) and dot(z_row, a2)
    float p1 = acc * a_w[lane];
    float p2 = acc * a_w[64 + lane];
    #pragma unroll
    for (int off = 32; off > 0; off >>= 1) {
        p1 += __shfl_xor(p1, off, 64);
        p2 += __shfl_xor(p2, off, 64);
    }
    if (lane == 0) { s_dst[node] = p1; s_src[node] = p2; }
}

// ---------------------------------------------------------------------------
// K2: per-edge unnormalized attention h = exp(leakyrelu(sd+ss+b));
//     segment-sum into h_sum[dst] via atomics. h written to alpha section.
// ---------------------------------------------------------------------------
__global__ __launch_bounds__(256) void k2_edge_scores(
    const int* __restrict__ ei,
    const float* __restrict__ s_dst, const float* __restrict__ s_src,
    const float* __restrict__ a_b,
    float* __restrict__ h_raw, float* __restrict__ h_sum)
{
    const int e = blockIdx.x * 256 + threadIdx.x;
    if (e >= N_EDGES) return;
    const int d = ei[e];
    const int s = ei[N_EDGES + e];
    float h = s_dst[d] + s_src[s] + a_b[0];
    h = (h >= 0.f) ? h : LRELU_ALPHA * h;
    h = expf(h);
    h_raw[e] = h;
    atomicAdd(&h_sum[d], h);
}

// ---------------------------------------------------------------------------
// K3: alpha = h / h_sum[dst] (written in place over h_raw);
//     out[dst,:] += alpha * z[src,:].  One wave per edge, lane = hidden unit.
// ---------------------------------------------------------------------------
__global__ __launch_bounds__(256) void k3_aggregate(
    const int* __restrict__ ei, const float* __restrict__ z,
    const float* __restrict__ h_sum,
    float* __restrict__ alpha, float* __restrict__ out)
{
    const int wid  = (blockIdx.x * 256 + threadIdx.x) >> 6;  // edge id
    const int lane = threadIdx.x & 63;
    if (wid >= N_EDGES) return;

    const int d = ei[wid];
    const int s = ei[N_EDGES + wid];
    const float a = alpha[wid] / h_sum[d];   // broadcast loads (same addr)
    if (lane == 0) alpha[wid] = a;           // finalize alpha output

    atomicAdd(&out[d * N_HIDDEN + lane], a * z[s * N_HIDDEN + lane]);
}

// ---------------------------------------------------------------------------
extern "C" void kernel_launch(void* const* d_in, const int* in_sizes, int n_in,
                              void* d_out, int out_size, void* d_ws, size_t ws_size,
                              hipStream_t stream) {
    const float* x   = (const float*)d_in[0];
    const int*   ei  = (const int*)d_in[1];   // [2*E]: row0 = dst, row1 = src
    const float* W   = (const float*)d_in[2];
    const float* a_w = (const float*)d_in[3];
    const float* a_b = (const float*)d_in[4];

    float* out   = (float*)d_out;                 // [N*64]
    float* alpha = out + (size_t)N_NODES * N_HIDDEN; // [E]

    float* z     = (float*)d_ws;                  // [N*64]
    float* s_dst = z + (size_t)N_NODES * N_HIDDEN; // [N]
    float* s_src = s_dst + N_NODES;               // [N]
    float* h_sum = s_src + N_NODES;               // [N]

    // zero the accumulation targets (graph-capture safe)
    hipMemsetAsync(out, 0, (size_t)N_NODES * N_HIDDEN * sizeof(float), stream);
    hipMemsetAsync(h_sum, 0, (size_t)N_NODES * sizeof(float), stream);

    k1_fc_scores<<<(N_NODES + 3) / 4, 256, 0, stream>>>(x, W, a_w, z, s_dst, s_src);
    k2_edge_scores<<<(N_EDGES + 255) / 256, 256, 0, stream>>>(ei, s_dst, s_src, a_b, alpha, h_sum);
    k3_aggregate<<<(N_EDGES + 3) / 4, 256, 0, stream>>>(ei, z, h_sum, alpha, out);
}